// Round 1
// baseline (47.203 us; speedup 1.0000x reference)
//
#include <hip/hip_runtime.h>
#include <hip/hip_bf16.h>

typedef __attribute__((ext_vector_type(8))) short bf16x8;
typedef __attribute__((ext_vector_type(4))) float f32x4;

static __device__ __forceinline__ unsigned short f2bf(float f) {
    unsigned int u = __float_as_uint(f);
    unsigned int rnd = 0x7FFFu + ((u >> 16) & 1u);
    return (unsigned short)((u + rnd) >> 16);
}

// ---------------- Kernel 1: hypernetwork hw = hyper@W1+b1, bias = hyper@Wb+bb
__global__ void hypernet_kernel(const float* __restrict__ hyper,   // (8,256)
                                const float* __restrict__ W1,      // (256,4096)
                                const float* __restrict__ b1,      // (4096)
                                const float* __restrict__ Wb,      // (256,64)
                                const float* __restrict__ bb,      // (64)
                                float* __restrict__ hw,            // ws: 8*4096
                                float* __restrict__ bias)          // ws: 8*64
{
    int idx = blockIdx.x * blockDim.x + threadIdx.x;
    if (idx < 8 * 4096) {
        int h = idx >> 12, j = idx & 4095;
        const float* hr = hyper + h * 256;
        float acc = b1[j];
        #pragma unroll 4
        for (int d = 0; d < 256; ++d) acc += hr[d] * W1[d * 4096 + j];
        hw[idx] = acc;
    } else if (idx < 8 * 4096 + 8 * 64) {
        int t = idx - 8 * 4096;
        int h = t >> 6, s = t & 63;
        const float* hr = hyper + h * 256;
        float acc = bb[s];
        #pragma unroll 4
        for (int d = 0; d < 256; ++d) acc += hr[d] * Wb[d * 64 + s];
        bias[t] = acc;
    }
}

// ---------------- Kernel 2: W[h] = down@up, packed directly into MFMA
// B-fragment order for v_mfma_f32_16x16x32_bf16.
// packed[((n*2+kap)*64 + lane)*8 + b] = bf16( Wcat[kap*32 + (lane>>4)*8 + b,
//                                                  n*16 + (lane&15)] )
// where Wcat[k, h*64+s] = W[h][k][s] = sum_r down[h,k,r]*up[h,r,s].
__global__ void pack_kernel(const float* __restrict__ hw,          // 8*4096
                            unsigned short* __restrict__ packed)   // 32768 bf16
{
    int p = blockIdx.x * blockDim.x + threadIdx.x;  // 0..32767
    int b   = p & 7;
    int l   = (p >> 3) & 63;
    int kap = (p >> 9) & 1;
    int n   = p >> 10;                              // 0..31
    int k   = kap * 32 + ((l >> 4) << 3) + b;       // 0..63 (= target feature d)
    int col = (n << 4) + (l & 15);                  // 0..511
    int h = col >> 6, s = col & 63;
    const float* hwh = hw + h * 4096;
    float acc = 0.f;
    #pragma unroll
    for (int r = 0; r < 32; ++r)
        acc += hwh[k * 32 + r] * hwh[2048 + r * 64 + s];
    packed[p] = f2bf(acc);
}

// ---------------- Kernel 3: main GEMM + masked H-reduction epilogue
// Z = X(M x 64) @ Wcat(64 x 512), out[row,s] = sum_h m[row,h]*(Z[row,h*64+s]+bias[h,s])
#define ROWS 128

__global__ __launch_bounds__(256)
void main_kernel(const float* __restrict__ X,       // (M,64)
                 const float* __restrict__ Mask,    // (M,8)
                 const unsigned short* __restrict__ packedB,
                 const float* __restrict__ bias,    // (8,64)
                 float* __restrict__ Out)           // (M,64)
{
    __shared__ __align__(16) unsigned short sX[ROWS * 64]; // bf16, XOR-swizzled
    __shared__ __align__(16) float sM[ROWS * 8];
    __shared__ __align__(16) float sB[8 * 64];

    const int tid  = threadIdx.x;
    const int lane = tid & 63;
    const int w    = tid >> 6;          // wave id 0..3 -> s-tile w
    const long rowBase = (long)blockIdx.x * ROWS;

    // ---- stage X tile as bf16 with XOR swizzle (breaks 128B-row bank conflict)
    {
        const float4* Xv = (const float4*)(X + rowBase * 64);
        #pragma unroll
        for (int it = 0; it < (ROWS * 16) / 256; ++it) {
            int f = it * 256 + tid;     // float4 index, 16 per row
            int row = f >> 4;
            int q   = f & 15;
            float4 v = Xv[f];
            ushort4 bv;
            bv.x = f2bf(v.x); bv.y = f2bf(v.y); bv.z = f2bf(v.z); bv.w = f2bf(v.w);
            int idx = row * 64 + ((q * 4) ^ ((row & 7) << 3));  // ushort units
            *(ushort4*)(&sX[idx]) = bv;
        }
    }
    // ---- stage mask tile (128 x 8 f32)
    {
        const float4* Mv = (const float4*)(Mask + rowBase * 8);
        float4 v = Mv[tid];             // 256 float4 = whole tile
        *(float4*)(&sM[tid * 4]) = v;
    }
    // ---- stage bias (8 x 64 f32)
    if (tid < 128) ((float4*)sB)[tid] = ((const float4*)bias)[tid];
    __syncthreads();

    // ---- per-wave B fragments in registers: n-tile = h*4 + w  (cols h*64 + w*16 ..)
    bf16x8 Bf[8][2];
    #pragma unroll
    for (int h = 0; h < 8; ++h) {
        #pragma unroll
        for (int kap = 0; kap < 2; ++kap) {
            int n = h * 4 + w;
            Bf[h][kap] = *(const bf16x8*)(packedB + ((((n * 2 + kap) * 64) + lane) << 3));
        }
    }

    const int c = lane & 15;            // A row-within-tile / D col-within-tile
    const int g = lane >> 4;            // k-group / D row-group
    const int s = w * 16 + c;           // output column 0..63

    // hoist bias for this lane's column
    float biasr[8];
    #pragma unroll
    for (int h = 0; h < 8; ++h) biasr[h] = sB[h * 64 + s];

    #pragma unroll 2
    for (int rt = 0; rt < ROWS / 16; ++rt) {
        const int arow = rt * 16 + c;
        const int sw = (arow & 7) << 3;
        bf16x8 a0 = *(const bf16x8*)(&sX[arow * 64 + ((g * 8) ^ sw)]);
        bf16x8 a1 = *(const bf16x8*)(&sX[arow * 64 + (((g + 4) * 8) ^ sw)]);

        f32x4 acc[8];
        #pragma unroll
        for (int h = 0; h < 8; ++h) acc[h] = (f32x4)(0.f);
        #pragma unroll
        for (int h = 0; h < 8; ++h) {
            acc[h] = __builtin_amdgcn_mfma_f32_16x16x32_bf16(a0, Bf[h][0], acc[h], 0, 0, 0);
            acc[h] = __builtin_amdgcn_mfma_f32_16x16x32_bf16(a1, Bf[h][1], acc[h], 0, 0, 0);
        }

        // epilogue: out[row,s] = sum_h m[row,h] * (Z + bias)
        #pragma unroll
        for (int i = 0; i < 4; ++i) {
            int r = rt * 16 + g * 4 + i;
            float o = 0.f;
            #pragma unroll
            for (int h = 0; h < 8; ++h)
                o += sM[r * 8 + h] * (acc[h][i] + biasr[h]);
            Out[(rowBase + r) * 64 + s] = o;
        }
    }
}

extern "C" void kernel_launch(void* const* d_in, const int* in_sizes, int n_in,
                              void* d_out, int out_size, void* d_ws, size_t ws_size,
                              hipStream_t stream) {
    const float* target = (const float*)d_in[0];   // (B,L,64)
    const float* hyper  = (const float*)d_in[1];   // (8,256)
    const float* mask   = (const float*)d_in[2];   // (B,L,8)
    const float* W1     = (const float*)d_in[3];   // (256,4096)
    const float* b1     = (const float*)d_in[4];   // (4096)
    const float* Wb     = (const float*)d_in[5];   // (256,64)
    const float* bb     = (const float*)d_in[6];   // (64)
    float* out = (float*)d_out;

    float* hw   = (float*)d_ws;                         // 32768 f32
    float* bias = hw + 8 * 4096;                        // 512 f32
    unsigned short* packed = (unsigned short*)(bias + 512); // 32768 bf16

    const int M = in_sizes[0] / 64;                     // 131072 rows

    hipLaunchKernelGGL(hypernet_kernel, dim3((8 * 4096 + 8 * 64 + 255) / 256), dim3(256),
                       0, stream, hyper, W1, b1, Wb, bb, hw, bias);
    hipLaunchKernelGGL(pack_kernel, dim3(32768 / 256), dim3(256), 0, stream, hw, packed);
    hipLaunchKernelGGL(main_kernel, dim3(M / ROWS), dim3(256), 0, stream,
                       target, mask, packed, bias, out);
}